// Round 8
// baseline (160.787 us; speedup 1.0000x reference)
//
#include <hip/hip_runtime.h>
#include <hip/hip_fp16.h>

#define NB 512
#define NN 50
#define ND 64
#define LOG2E 1.44269504088896340736f

typedef short bf16x8 __attribute__((ext_vector_type(8)));
typedef float f32x4  __attribute__((ext_vector_type(4)));
typedef _Float16 h2  __attribute__((ext_vector_type(2)));

// ---- manual LDS arena (bytes) ----
// xa   u16 [64][72]   9216 @ 0     : layer input x / att1 (bf16 MFMA-A rows; rows 50-63 zero)
// wa1t u16 [64][72]   9216 @ 9216  : Wa1^T [n][k]
// wa2t u16 [64][72]   9216 @ 18432 : Wa2^T [n][k]
// wot  u16 [64][72]   9216 @ 27648 : W1^T then W2^T
// kx   f16 [64][108] 13824 @ 36864 : per d, 27 4-u16 records [Ek2p,Ek2p+1,ek2p,ek2p+1]
//                                    (stride 216B: 8B-aligned b64, 16 bank-bases -> 2-way=free)
// xt   f16 [64][60]   7680 @ 50688 : x transposed [d][j], stride 120B (b32 pair loads)
// qrho f16 [50][66]   6600 @ 58368 : rho = exp(-.99 q'), [i][d]
// alias xb u16[64][72] 9216 @ 36864 (over kx head; kx dead after ph2, barrier-guarded)
// alias yF f32[50][64] 12800 @ 46080 (over kx tail + xt + qrho head; all dead in L1 ph3)
#define OFF_XA    0
#define OFF_WA1T  9216
#define OFF_WA2T  18432
#define OFF_WOT   27648
#define OFF_KX    36864
#define OFF_XT    50688
#define OFF_QRHO  58368
#define OFF_XB    36864
#define OFF_YF    46080
#define SMEM_BYTES 64968

__device__ __forceinline__ float bfu(unsigned short u) {
    union { unsigned int i; float f; } v; v.i = ((unsigned int)u) << 16; return v.f;
}
__device__ __forceinline__ unsigned int f2bfbits(float f) {
    union { float f; unsigned int i; } v; v.f = f;
    unsigned int x = v.i;
    return (x + 0x7FFFu + ((x >> 16) & 1u)) >> 16;
}
__device__ __forceinline__ h2 u2h2(unsigned int u) {
    union { unsigned int i; h2 h; } v; v.i = u; return v.h;
}
__device__ __forceinline__ float fdot2acc(h2 a, h2 b, float c) {
#if __has_builtin(__builtin_amdgcn_fdot2)
    return __builtin_amdgcn_fdot2(a, b, c, false);   // v_dot2_f32_f16
#else
    return c + (float)a.x * (float)b.x + (float)a.y * (float)b.y;
#endif
}

// One block per batch, 1024 threads = 16 waves (2 blocks/CU).
// MFMA 16x16x32_bf16, M padded 50->64, 4x4 tile grid, 1 tile/wave.
// Phase 2 packed f16: w_ij = Eq*max(Ek, rho*ek), rho = exp2(-0.99q'); Eq cancels.
// Inner loop per j-pair: 1 ds_read_b64 (Ek2|ek2) + 1 ds_read_b32 (x2) +
// 4 packed ops per row (pk_mul, pk_max, 2x v_dot2_f32_f16 accumulating f32).
__global__ __launch_bounds__(1024, 8)
void att2_kernel(const float* __restrict__ emb,
                 const float* __restrict__ wa1, const float* __restrict__ ba1,
                 const float* __restrict__ wa2, const float* __restrict__ ba2,
                 const float* __restrict__ w1,  const float* __restrict__ b1,
                 const float* __restrict__ w2,  const float* __restrict__ b2,
                 float* __restrict__ out)
{
    __shared__ __align__(16) unsigned char smem[SMEM_BYTES];
    unsigned short* xa   = (unsigned short*)(smem + OFF_XA);
    unsigned short* wa1t = (unsigned short*)(smem + OFF_WA1T);
    unsigned short* wa2t = (unsigned short*)(smem + OFF_WA2T);
    unsigned short* wot  = (unsigned short*)(smem + OFF_WOT);
    _Float16*       kx   = (_Float16*)(smem + OFF_KX);
    _Float16*       xt   = (_Float16*)(smem + OFF_XT);
    _Float16*       qrho = (_Float16*)(smem + OFF_QRHO);
    unsigned short* xb   = (unsigned short*)(smem + OFF_XB);   // alias
    float*          yF   = (float*)(smem + OFF_YF);            // alias

    const int b    = blockIdx.x;
    const int tid  = threadIdx.x;
    const int w    = tid >> 6;        // wave 0..15
    const int lane = tid & 63;
    const int ln   = lane & 15;       // MFMA row/col in tile
    const int qd   = lane >> 4;       // MFMA quad
    const int tm   = w >> 2;          // M-tile
    const int tn   = w & 3;           // N-tile
    const int d    = lane;            // phase-2 column
    const int iq   = w;               // phase-2 row group
    const bool has3 = (iq < 2);       // row iq+48 valid

    const float* embB = emb + (size_t)b * (NN + 1) * ND;

    // ---- phase 0: stage x (bf16 rows + f16 transposed), zero xa pad, W^T ----
    for (int u = tid; u < (NN * ND) / 2; u += 1024) {
        float2 v = *(const float2*)(embB + ND + 2 * u);
        int i = (2 * u) >> 6, c = (2 * u) & 63;
        *(unsigned int*)&xa[i * 72 + c] = (f2bfbits(v.y) << 16) | f2bfbits(v.x);
        xt[c * 60 + i]       = (_Float16)v.x;
        xt[(c + 1) * 60 + i] = (_Float16)v.y;
    }
    for (int u = tid; u < 14 * 72; u += 1024) xa[NN * 72 + u] = 0;   // A pad rows
    for (int u = tid; u < ND * ND; u += 1024) {
        int k = u >> 6, n = u & 63;
        wa1t[n * 72 + k] = (unsigned short)f2bfbits(wa1[u]);
        wa2t[n * 72 + k] = (unsigned short)f2bfbits(wa2[u]);
        wot [n * 72 + k] = (unsigned short)f2bfbits(w1[u]);
    }
    __syncthreads();

    const float bq = ba1[tn * 16 + ln];
    const float bk = ba2[tn * 16 + ln];

    for (int L = 0; L < 2; ++L) {
        if (L == 1) {   // restage W2^T; next read is >=2 barriers ahead
            for (int u = tid; u < ND * ND; u += 1024) {
                int k = u >> 6, n = u & 63;
                wot[n * 72 + k] = (unsigned short)f2bfbits(w2[u]);
            }
        }

        // ---- phase 1: q/k GEMM on MFMA + exp epilogue ----
        {
            const bf16x8 a0 = *(const bf16x8*)&xa[(tm * 16 + ln) * 72 + qd * 8];
            const bf16x8 a1 = *(const bf16x8*)&xa[(tm * 16 + ln) * 72 + 32 + qd * 8];
            f32x4 accq = {bq, bq, bq, bq};
            f32x4 acck = {bk, bk, bk, bk};

            bf16x8 bf_;
            bf_ = *(const bf16x8*)&wa1t[(tn * 16 + ln) * 72 + qd * 8];
            accq = __builtin_amdgcn_mfma_f32_16x16x32_bf16(a0, bf_, accq, 0, 0, 0);
            bf_ = *(const bf16x8*)&wa1t[(tn * 16 + ln) * 72 + 32 + qd * 8];
            accq = __builtin_amdgcn_mfma_f32_16x16x32_bf16(a1, bf_, accq, 0, 0, 0);
            bf_ = *(const bf16x8*)&wa2t[(tn * 16 + ln) * 72 + qd * 8];
            acck = __builtin_amdgcn_mfma_f32_16x16x32_bf16(a0, bf_, acck, 0, 0, 0);
            bf_ = *(const bf16x8*)&wa2t[(tn * 16 + ln) * 72 + 32 + qd * 8];
            acck = __builtin_amdgcn_mfma_f32_16x16x32_bf16(a1, bf_, acck, 0, 0, 0);

            const int dcol = tn * 16 + ln;
            _Float16* kxd = kx + dcol * 108;
#pragma unroll
            for (int reg = 0; reg < 4; ++reg) {
                const int i = tm * 16 + qd * 4 + reg;
                if (i < NN) {
                    float rho = __builtin_exp2f(accq[reg] * (-0.99f * LOG2E));
                    float kp  = acck[reg] * LOG2E;
                    qrho[i * 66 + dcol]          = (_Float16)rho;
                    kxd[(i >> 1) * 4 + (i & 1)]      = (_Float16)__builtin_exp2f(kp);
                    kxd[(i >> 1) * 4 + 2 + (i & 1)]  = (_Float16)__builtin_exp2f(0.01f * kp);
                }
            }
        }
        __syncthreads();

        // ---- phase 2: packed-f16 softmax-weighted sum, f32 dot2 accumulate ----
        float att[4];
        {
            h2 rho2[4];
            float num[4], den[4];
#pragma unroll
            for (int r = 0; r < 4; ++r) { num[r] = 0.f; den[r] = 0.f; rho2[r] = (h2)0.f; }
#pragma unroll
            for (int r = 0; r < 3; ++r) {
                _Float16 rv = qrho[(iq + 16 * r) * 66 + d];
                rho2[r] = (h2){rv, rv};
            }
            if (has3) {
                _Float16 rv = qrho[(iq + 48) * 66 + d];
                rho2[3] = (h2){rv, rv};
            }
            const h2 ones = {(_Float16)1.f, (_Float16)1.f};

            const uint2* kxP = (const uint2*)(kx + d * 108);
            const h2*    xP  = (const h2*)(xt + d * 60);
            for (int p = 0; p < NN / 2; ++p) {
                uint2 kv = kxP[p];              // ds_read_b64: (Ek2, ek2)
                h2 Ek2 = u2h2(kv.x);
                h2 ek2 = u2h2(kv.y);
                h2 x2  = xP[p];                 // ds_read_b32
#pragma unroll
                for (int r = 0; r < 3; ++r) {
                    h2 wv = __builtin_elementwise_max(rho2[r] * ek2, Ek2);
                    den[r] = fdot2acc(wv, ones, den[r]);
                    num[r] = fdot2acc(wv, x2,   num[r]);
                }
                if (has3) {
                    h2 wv = __builtin_elementwise_max(rho2[3] * ek2, Ek2);
                    den[3] = fdot2acc(wv, ones, den[3]);
                    num[3] = fdot2acc(wv, x2,   num[3]);
                }
            }
#pragma unroll
            for (int r = 0; r < 4; ++r) att[r] = num[r] / den[r];
        }
        __syncthreads();                 // kx fully read -> safe to alias xb
        {
#pragma unroll
            for (int r = 0; r < 3; ++r)
                xb[(iq + 16 * r) * 72 + d] = (unsigned short)f2bfbits(att[r]);
            if (has3)
                xb[(iq + 48) * 72 + d] = (unsigned short)f2bfbits(att[3]);
        }
        __syncthreads();

        // ---- phase 3: y = att @ Wl + bl on MFMA ----
        // (xb pad rows 50-63 hold stale data: A-row garbage only affects
        //  C-rows >=50, which are discarded.)
        {
            const bf16x8 c0 = *(const bf16x8*)&xb[(tm * 16 + ln) * 72 + qd * 8];
            const bf16x8 c1 = *(const bf16x8*)&xb[(tm * 16 + ln) * 72 + 32 + qd * 8];
            const float bov = (L ? b2 : b1)[tn * 16 + ln];
            f32x4 y = {bov, bov, bov, bov};

            bf16x8 bf_;
            bf_ = *(const bf16x8*)&wot[(tn * 16 + ln) * 72 + qd * 8];
            y = __builtin_amdgcn_mfma_f32_16x16x32_bf16(c0, bf_, y, 0, 0, 0);
            bf_ = *(const bf16x8*)&wot[(tn * 16 + ln) * 72 + 32 + qd * 8];
            y = __builtin_amdgcn_mfma_f32_16x16x32_bf16(c1, bf_, y, 0, 0, 0);

            const int dcol = tn * 16 + ln;
            if (L == 0) {
                // att1 -> xa (bf16 rows) and xt (f16 [d][j]) for L1
#pragma unroll
                for (int reg = 0; reg < 4; ++reg) {
                    const int i = tm * 16 + qd * 4 + reg;
                    if (i < NN) {
                        xa[i * 72 + dcol] = (unsigned short)f2bfbits(y[reg]);
                        xt[dcol * 60 + i] = (_Float16)y[reg];
                    }
                }
                __syncthreads();
            } else {
                // stage fp32 y over dead kx-tail/xt/qrho, then coalesced store
#pragma unroll
                for (int reg = 0; reg < 4; ++reg) {
                    const int i = tm * 16 + qd * 4 + reg;
                    if (i < NN) yF[i * 64 + dcol] = y[reg];
                }
                __syncthreads();
                for (int idx = tid; idx < NN * ND; idx += 1024) {
                    const int i  = idx >> 6;
                    const int dd = idx & 63;
                    float e0   = embB[dd];
                    float ie   = embB[ND + idx];
                    float att1 = bfu(xa[i * 72 + dd]);
                    float o    = fmaf(e0, ie, yF[idx] + att1);
                    o = fmaxf(o, 0.01f * o);
                    out[(size_t)b * (NN * ND) + idx] = o;
                }
            }
        }
    }
}

extern "C" void kernel_launch(void* const* d_in, const int* in_sizes, int n_in,
                              void* d_out, int out_size, void* d_ws, size_t ws_size,
                              hipStream_t stream) {
    const float* emb = (const float*)d_in[0];
    const float* wa1 = (const float*)d_in[1];
    const float* ba1 = (const float*)d_in[2];
    const float* wa2 = (const float*)d_in[3];
    const float* ba2 = (const float*)d_in[4];
    const float* w1  = (const float*)d_in[5];
    const float* b1  = (const float*)d_in[6];
    const float* w2  = (const float*)d_in[7];
    const float* b2  = (const float*)d_in[8];
    float* out = (float*)d_out;

    att2_kernel<<<NB, 1024, 0, stream>>>(emb, wa1, ba1, wa2, ba2, w1, b1, w2, b2, out);
}

// Round 9
// 97.945 us; speedup vs baseline: 1.6416x; 1.6416x over previous
//
#include <hip/hip_runtime.h>
#include <hip/hip_fp16.h>

#define NB 512
#define NN 50
#define ND 64
#define LOG2E 1.44269504088896340736f

typedef short bf16x8 __attribute__((ext_vector_type(8)));
typedef float f32x4  __attribute__((ext_vector_type(4)));
typedef _Float16 h2  __attribute__((ext_vector_type(2)));

// ---- manual LDS arena (bytes) ----
// xa   u16 [64][72]   9216 @ 0     : layer input x / att1 (bf16 MFMA-A rows; rows 50-63 zero)
// wa1t u16 [64][72]   9216 @ 9216  : Wa1^T [n][k]
// wa2t u16 [64][72]   9216 @ 18432 : Wa2^T [n][k]
// wot  u16 [64][72]   9216 @ 27648 : W1^T then W2^T
// kx2  f16 [64][110] 14080 @ 36864 : per d, h2 records: [2p]=Ek pair, [2p+1]=ek pair
//                                    (row stride 220 B; adjacent aligned h2 -> 1 ds_read_b64/pair)
// xt   f16 [64][54]   6912 @ 50944 : x transposed [d][j] (dword stride 27: all banks)
// qrho f16 [50][66]   6600 @ 57856 : rho = exp(-.99 q'), [i][d]
// alias xb u16[64][72] 9216 @ 36864 (over kx2 head; kx2 dead after ph2, barrier-guarded)
// alias yF f32[50][64] 12800 @ 46080 (over kx2 tail + xt + qrho; all dead in L1 ph3; disjoint from xb/xa/wot)
#define OFF_XA    0
#define OFF_WA1T  9216
#define OFF_WA2T  18432
#define OFF_WOT   27648
#define OFF_KX2   36864
#define OFF_XT    50944
#define OFF_QRHO  57856
#define OFF_XB    36864
#define OFF_YF    46080
#define SMEM_BYTES 64464

__device__ __forceinline__ float bfu(unsigned short u) {
    union { unsigned int i; float f; } v; v.i = ((unsigned int)u) << 16; return v.f;
}
__device__ __forceinline__ unsigned int f2bfbits(float f) {
    union { float f; unsigned int i; } v; v.f = f;
    unsigned int x = v.i;
    return (x + 0x7FFFu + ((x >> 16) & 1u)) >> 16;
}

// One block per batch, 1024 threads = 16 waves (2 blocks/CU).
// MFMA 16x16x32_bf16, M padded 50->64, 4x4 tile grid, 1 tile/wave.
// Phase 2 packed f16 (v_pk_*): w_ij = Eq*max(Ek, rho*ek), rho = exp2(-0.99q');
// Eq cancels in num/den. NO unions over vector types (r8: that pattern forced
// scratch round-trips -> 300 MB HBM traffic, 2.5x regression).
__global__ __launch_bounds__(1024, 8)
void att2_kernel(const float* __restrict__ emb,
                 const float* __restrict__ wa1, const float* __restrict__ ba1,
                 const float* __restrict__ wa2, const float* __restrict__ ba2,
                 const float* __restrict__ w1,  const float* __restrict__ b1,
                 const float* __restrict__ w2,  const float* __restrict__ b2,
                 float* __restrict__ out)
{
    __shared__ __align__(16) unsigned char smem[SMEM_BYTES];
    unsigned short* xa   = (unsigned short*)(smem + OFF_XA);
    unsigned short* wa1t = (unsigned short*)(smem + OFF_WA1T);
    unsigned short* wa2t = (unsigned short*)(smem + OFF_WA2T);
    unsigned short* wot  = (unsigned short*)(smem + OFF_WOT);
    _Float16*       kx   = (_Float16*)(smem + OFF_KX2);
    _Float16*       xt   = (_Float16*)(smem + OFF_XT);
    _Float16*       qrho = (_Float16*)(smem + OFF_QRHO);
    unsigned short* xb   = (unsigned short*)(smem + OFF_XB);   // alias
    float*          yF   = (float*)(smem + OFF_YF);            // alias

    const int b    = blockIdx.x;
    const int tid  = threadIdx.x;
    const int w    = tid >> 6;        // wave 0..15
    const int lane = tid & 63;
    const int ln   = lane & 15;       // MFMA row/col in tile
    const int qd   = lane >> 4;       // MFMA quad
    const int tm   = w >> 2;          // M-tile
    const int tn   = w & 3;           // N-tile
    const int d    = lane;            // phase-2 column
    const int iq   = w;               // phase-2 row group
    const bool has3 = (iq < 2);       // row iq+48 valid

    const float* embB = emb + (size_t)b * (NN + 1) * ND;

    // ---- phase 0: stage x (bf16 rows + f16 transposed), zero xa pad, W^T ----
    for (int u = tid; u < (NN * ND) / 2; u += 1024) {
        float2 v = *(const float2*)(embB + ND + 2 * u);
        int i = (2 * u) >> 6, c = (2 * u) & 63;
        *(unsigned int*)&xa[i * 72 + c] = (f2bfbits(v.y) << 16) | f2bfbits(v.x);
        xt[c * 54 + i]       = (_Float16)v.x;
        xt[(c + 1) * 54 + i] = (_Float16)v.y;
    }
    for (int u = tid; u < 14 * 72; u += 1024) xa[NN * 72 + u] = 0;   // A pad rows
    for (int u = tid; u < ND * ND; u += 1024) {
        int k = u >> 6, n = u & 63;
        wa1t[n * 72 + k] = (unsigned short)f2bfbits(wa1[u]);
        wa2t[n * 72 + k] = (unsigned short)f2bfbits(wa2[u]);
        wot [n * 72 + k] = (unsigned short)f2bfbits(w1[u]);
    }
    __syncthreads();

    const float bq = ba1[tn * 16 + ln];
    const float bk = ba2[tn * 16 + ln];

    for (int L = 0; L < 2; ++L) {
        if (L == 1) {   // restage W2^T; last wot read was before the prev barrier
            for (int u = tid; u < ND * ND; u += 1024) {
                int k = u >> 6, n = u & 63;
                wot[n * 72 + k] = (unsigned short)f2bfbits(w2[u]);
            }
        }

        // ---- phase 1: q/k GEMM on MFMA + exp epilogue ----
        {
            const bf16x8 a0 = *(const bf16x8*)&xa[(tm * 16 + ln) * 72 + qd * 8];
            const bf16x8 a1 = *(const bf16x8*)&xa[(tm * 16 + ln) * 72 + 32 + qd * 8];
            f32x4 accq = {bq, bq, bq, bq};
            f32x4 acck = {bk, bk, bk, bk};

            bf16x8 bf_;
            bf_ = *(const bf16x8*)&wa1t[(tn * 16 + ln) * 72 + qd * 8];
            accq = __builtin_amdgcn_mfma_f32_16x16x32_bf16(a0, bf_, accq, 0, 0, 0);
            bf_ = *(const bf16x8*)&wa1t[(tn * 16 + ln) * 72 + 32 + qd * 8];
            accq = __builtin_amdgcn_mfma_f32_16x16x32_bf16(a1, bf_, accq, 0, 0, 0);
            bf_ = *(const bf16x8*)&wa2t[(tn * 16 + ln) * 72 + qd * 8];
            acck = __builtin_amdgcn_mfma_f32_16x16x32_bf16(a0, bf_, acck, 0, 0, 0);
            bf_ = *(const bf16x8*)&wa2t[(tn * 16 + ln) * 72 + 32 + qd * 8];
            acck = __builtin_amdgcn_mfma_f32_16x16x32_bf16(a1, bf_, acck, 0, 0, 0);

            const int dcol = tn * 16 + ln;
            _Float16* kxd = kx + dcol * 110;
#pragma unroll
            for (int reg = 0; reg < 4; ++reg) {
                const int i = tm * 16 + qd * 4 + reg;
                if (i < NN) {
                    float rho = __builtin_exp2f(accq[reg] * (-0.99f * LOG2E));
                    float kp  = acck[reg] * LOG2E;
                    qrho[i * 66 + dcol] = (_Float16)rho;
                    kxd[(i >> 1) * 4 + (i & 1)]     = (_Float16)__builtin_exp2f(kp);
                    kxd[(i >> 1) * 4 + 2 + (i & 1)] = (_Float16)__builtin_exp2f(0.01f * kp);
                }
            }
        }
        __syncthreads();

        // ---- phase 2: packed-f16 softmax-weighted sum, 2 j's per op ----
        float att[4];
        {
            h2 rho2[4], num2[4], den2[4];
#pragma unroll
            for (int r = 0; r < 4; ++r) {
                num2[r] = (h2)0.f; den2[r] = (h2)0.f; rho2[r] = (h2)0.f;
            }
#pragma unroll
            for (int r = 0; r < 3; ++r) {
                _Float16 rv = qrho[(iq + 16 * r) * 66 + d];
                rho2[r] = (h2){rv, rv};
            }
            if (has3) {
                _Float16 rv = qrho[(iq + 48) * 66 + d];
                rho2[3] = (h2){rv, rv};
            }

            const h2* kxd = (const h2*)(kx + d * 110);   // typed h2 loads, no unions
            const h2* xP  = (const h2*)(xt + d * 54);
            for (int p = 0; p < NN / 2; ++p) {
                h2 Ek2 = kxd[2 * p];        // adjacent + 8B-aligned -> merged b64
                h2 ek2 = kxd[2 * p + 1];
                h2 x2  = xP[p];
#pragma unroll
                for (int r = 0; r < 3; ++r) {
                    h2 wv = __builtin_elementwise_max(rho2[r] * ek2, Ek2);
                    den2[r] = den2[r] + wv;
                    num2[r] = wv * x2 + num2[r];        // v_pk_fma_f16
                }
                if (has3) {
                    h2 wv = __builtin_elementwise_max(rho2[3] * ek2, Ek2);
                    den2[3] = den2[3] + wv;
                    num2[3] = wv * x2 + num2[3];
                }
            }
#pragma unroll
            for (int r = 0; r < 4; ++r) {
                float nu = (float)num2[r].x + (float)num2[r].y;
                float de = (float)den2[r].x + (float)den2[r].y;
                att[r] = nu / de;
            }
        }
        __syncthreads();                 // kx2 fully read -> safe to alias xb
        {
#pragma unroll
            for (int r = 0; r < 3; ++r)
                xb[(iq + 16 * r) * 72 + d] = (unsigned short)f2bfbits(att[r]);
            if (has3)
                xb[(iq + 48) * 72 + d] = (unsigned short)f2bfbits(att[3]);
        }
        __syncthreads();

        // ---- phase 3: y = att @ Wl + bl on MFMA ----
        // (xb pad rows 50-63 hold stale data: garbage A-rows only affect
        //  C-rows >= 50, which are discarded.)
        {
            const bf16x8 c0 = *(const bf16x8*)&xb[(tm * 16 + ln) * 72 + qd * 8];
            const bf16x8 c1 = *(const bf16x8*)&xb[(tm * 16 + ln) * 72 + 32 + qd * 8];
            const float bov = (L ? b2 : b1)[tn * 16 + ln];
            f32x4 y = {bov, bov, bov, bov};

            bf16x8 bf_;
            bf_ = *(const bf16x8*)&wot[(tn * 16 + ln) * 72 + qd * 8];
            y = __builtin_amdgcn_mfma_f32_16x16x32_bf16(c0, bf_, y, 0, 0, 0);
            bf_ = *(const bf16x8*)&wot[(tn * 16 + ln) * 72 + 32 + qd * 8];
            y = __builtin_amdgcn_mfma_f32_16x16x32_bf16(c1, bf_, y, 0, 0, 0);

            const int dcol = tn * 16 + ln;
            if (L == 0) {
                // att1 -> xa (bf16 rows) and xt (f16 [d][j]) for L1
#pragma unroll
                for (int reg = 0; reg < 4; ++reg) {
                    const int i = tm * 16 + qd * 4 + reg;
                    if (i < NN) {
                        xa[i * 72 + dcol] = (unsigned short)f2bfbits(y[reg]);
                        xt[dcol * 54 + i] = (_Float16)y[reg];
                    }
                }
                __syncthreads();
            } else {
                // stage fp32 y over dead kx2-tail/xt/qrho, then coalesced store
#pragma unroll
                for (int reg = 0; reg < 4; ++reg) {
                    const int i = tm * 16 + qd * 4 + reg;
                    if (i < NN) yF[i * 64 + dcol] = y[reg];
                }
                __syncthreads();
                for (int idx = tid; idx < NN * ND; idx += 1024) {
                    const int i  = idx >> 6;
                    const int dd = idx & 63;
                    float e0   = embB[dd];
                    float ie   = embB[ND + idx];
                    float att1 = bfu(xa[i * 72 + dd]);
                    float o    = fmaf(e0, ie, yF[idx] + att1);
                    o = fmaxf(o, 0.01f * o);
                    out[(size_t)b * (NN * ND) + idx] = o;
                }
            }
        }
    }
}

extern "C" void kernel_launch(void* const* d_in, const int* in_sizes, int n_in,
                              void* d_out, int out_size, void* d_ws, size_t ws_size,
                              hipStream_t stream) {
    const float* emb = (const float*)d_in[0];
    const float* wa1 = (const float*)d_in[1];
    const float* ba1 = (const float*)d_in[2];
    const float* wa2 = (const float*)d_in[3];
    const float* ba2 = (const float*)d_in[4];
    const float* w1  = (const float*)d_in[5];
    const float* b1  = (const float*)d_in[6];
    const float* w2  = (const float*)d_in[7];
    const float* b2  = (const float*)d_in[8];
    float* out = (float*)d_out;

    att2_kernel<<<NB, 1024, 0, stream>>>(emb, wa1, ba1, wa2, ba2, w1, b1, w2, b2, out);
}

// Round 10
// 95.852 us; speedup vs baseline: 1.6774x; 1.0218x over previous
//
#include <hip/hip_runtime.h>

#define NB 512
#define NN 50
#define ND 64
#define LOG2E 1.44269504088896340736f

typedef short bf16x8 __attribute__((ext_vector_type(8)));
typedef float f32x4  __attribute__((ext_vector_type(4)));
typedef _Float16 h2  __attribute__((ext_vector_type(2)));

// ---- manual LDS arena (bytes) ----
// xa  u16 [64][72]  9216 @ 0     : layer input x / att1 (bf16 MFMA-A rows; pad rows zeroed once)
// wa1t u16[64][72]  9216 @ 9216  : Wa1^T [n][k]
// wa2t u16[64][72]  9216 @ 18432 : Wa2^T [n][k]
// wot  u16[64][72]  9216 @ 27648 : W1^T then W2^T
// kx  f16 [64][116] 14848 @ 36864: per d, records [4p..4p+3] = Ek_2p,Ek_2p+1,ek_2p,ek_2p+1
//                                  (stride 232 B: 8B-aligned b64 reads, 16 even bank-bases -> conflict-free)
// xt  f16 [64][56]  7168 @ 51712 : x transposed [d][j] (112 B rows, 16B-aligned, 2-way banks = free)
// alias xb u16[64][72] 9216 @ 36864 (over kx head; kx dead after ph2, barrier-guarded)
// alias yF f32[50][64] 12800 @ 46080 (over kx tail + xt; both dead in L1 ph3; disjoint from xb/wot)
#define OFF_XA    0
#define OFF_WA1T  9216
#define OFF_WA2T  18432
#define OFF_WOT   27648
#define OFF_KX    36864
#define OFF_XT    51712
#define OFF_XB    36864
#define OFF_YF    46080
#define SMEM_BYTES 58880

__device__ __forceinline__ float bfu(unsigned short u) {
    union { unsigned int i; float f; } v; v.i = ((unsigned int)u) << 16; return v.f;
}
__device__ __forceinline__ unsigned int f2bfbits(float f) {
    union { float f; unsigned int i; } v; v.f = f;
    unsigned int x = v.i;
    return (x + 0x7FFFu + ((x >> 16) & 1u)) >> 16;
}

// One block per batch, 1024 threads = 16 waves (2 blocks/CU = 32 waves/CU = max).
// MFMA 16x16x32_bf16, M padded 50->64, 4x4 tile grid, 1 tile/wave.
// Phase 2 inherits phase 1's C-fragment ownership: thread (wave w, lane) owns
// rows i0..i0+3 (i0 = tm*16+qd*4) at column dcol = tn*16+ln; rho = exp2(-0.99q')
// stays in VGPRs across the barrier (no qrho LDS round trip). Uniform 4 rows:
// pad rows >= 50 compute finite garbage contained to discarded C-rows.
// w_ij = Eq*max(Ek, rho*ek); Eq cancels in num/den.
// NO unions over vector types (r8: scratch round-trips -> 300 MB HBM, 2.5x).
__global__ __launch_bounds__(1024, 8)
void att2_kernel(const float* __restrict__ emb,
                 const float* __restrict__ wa1, const float* __restrict__ ba1,
                 const float* __restrict__ wa2, const float* __restrict__ ba2,
                 const float* __restrict__ w1,  const float* __restrict__ b1,
                 const float* __restrict__ w2,  const float* __restrict__ b2,
                 float* __restrict__ out)
{
    __shared__ __align__(16) unsigned char smem[SMEM_BYTES];
    unsigned short* xa   = (unsigned short*)(smem + OFF_XA);
    unsigned short* wa1t = (unsigned short*)(smem + OFF_WA1T);
    unsigned short* wa2t = (unsigned short*)(smem + OFF_WA2T);
    unsigned short* wot  = (unsigned short*)(smem + OFF_WOT);
    _Float16*       kx   = (_Float16*)(smem + OFF_KX);
    _Float16*       xt   = (_Float16*)(smem + OFF_XT);
    unsigned short* xb   = (unsigned short*)(smem + OFF_XB);   // alias
    float*          yF   = (float*)(smem + OFF_YF);            // alias

    const int b    = blockIdx.x;
    const int tid  = threadIdx.x;
    const int w    = tid >> 6;        // wave 0..15
    const int lane = tid & 63;
    const int ln   = lane & 15;       // MFMA row/col in tile
    const int qd   = lane >> 4;       // MFMA quad
    const int tm   = w >> 2;          // M-tile
    const int tn   = w & 3;           // N-tile
    const int dcol = tn * 16 + ln;    // owned column (phases 1,2,3)
    const int i0   = tm * 16 + qd * 4;// first owned row

    const float* embB = emb + (size_t)b * (NN + 1) * ND;

    // ---- phase 0: stage x (bf16 rows + f16 transposed), zero xa pad, W^T ----
    for (int u = tid; u < (NN * ND) / 2; u += 1024) {
        float2 v = *(const float2*)(embB + ND + 2 * u);
        int i = (2 * u) >> 6, c = (2 * u) & 63;
        *(unsigned int*)&xa[i * 72 + c] = (f2bfbits(v.y) << 16) | f2bfbits(v.x);
        xt[c * 56 + i]       = (_Float16)v.x;
        xt[(c + 1) * 56 + i] = (_Float16)v.y;
    }
    for (int u = tid; u < 14 * 72; u += 1024) xa[NN * 72 + u] = 0;   // A pad rows
    for (int u = tid; u < ND * ND; u += 1024) {
        int k = u >> 6, n = u & 63;
        wa1t[n * 72 + k] = (unsigned short)f2bfbits(wa1[u]);
        wa2t[n * 72 + k] = (unsigned short)f2bfbits(wa2[u]);
        wot [n * 72 + k] = (unsigned short)f2bfbits(w1[u]);
    }
    __syncthreads();

    const float bq = ba1[dcol];
    const float bk = ba2[dcol];

    for (int L = 0; L < 2; ++L) {
        if (L == 1) {   // restage W2^T; last wot read was before the prev barrier
            for (int u = tid; u < ND * ND; u += 1024) {
                int k = u >> 6, n = u & 63;
                wot[n * 72 + k] = (unsigned short)f2bfbits(w2[u]);
            }
        }

        // ---- phase 1: q/k GEMM on MFMA + exp epilogue (rho stays in regs) ----
        float rho[4];
        {
            const bf16x8 a0 = *(const bf16x8*)&xa[(tm * 16 + ln) * 72 + qd * 8];
            const bf16x8 a1 = *(const bf16x8*)&xa[(tm * 16 + ln) * 72 + 32 + qd * 8];
            f32x4 accq = {bq, bq, bq, bq};
            f32x4 acck = {bk, bk, bk, bk};

            bf16x8 bf_;
            bf_ = *(const bf16x8*)&wa1t[dcol * 72 + qd * 8];
            accq = __builtin_amdgcn_mfma_f32_16x16x32_bf16(a0, bf_, accq, 0, 0, 0);
            bf_ = *(const bf16x8*)&wa1t[dcol * 72 + 32 + qd * 8];
            accq = __builtin_amdgcn_mfma_f32_16x16x32_bf16(a1, bf_, accq, 0, 0, 0);
            bf_ = *(const bf16x8*)&wa2t[dcol * 72 + qd * 8];
            acck = __builtin_amdgcn_mfma_f32_16x16x32_bf16(a0, bf_, acck, 0, 0, 0);
            bf_ = *(const bf16x8*)&wa2t[dcol * 72 + 32 + qd * 8];
            acck = __builtin_amdgcn_mfma_f32_16x16x32_bf16(a1, bf_, acck, 0, 0, 0);

            _Float16 Ekf[4], ekf[4];
#pragma unroll
            for (int reg = 0; reg < 4; ++reg) {
                rho[reg] = __builtin_exp2f(accq[reg] * (-0.99f * LOG2E));
                float kp = acck[reg] * LOG2E;
                Ekf[reg] = (_Float16)__builtin_exp2f(kp);
                ekf[reg] = (_Float16)__builtin_exp2f(0.01f * kp);
            }
            if (i0 < NN) {   // rows >= 50 never read in phase 2 (p < 25)
                h2* kxP = (h2*)(kx + dcol * 116 + i0 * 2);   // 8B-aligned
                kxP[0] = (h2){Ekf[0], Ekf[1]};
                kxP[1] = (h2){ekf[0], ekf[1]};
                kxP[2] = (h2){Ekf[2], Ekf[3]};
                kxP[3] = (h2){ekf[2], ekf[3]};
            }
        }
        __syncthreads();

        // ---- phase 2: packed-f16 softmax-weighted sum, uniform 4 rows ----
        float att[4];
        {
            h2 rho2[4], num2[4], den2[4];
#pragma unroll
            for (int r = 0; r < 4; ++r) {
                _Float16 rv = (_Float16)rho[r];
                rho2[r] = (h2){rv, rv};
                num2[r] = (h2)0.f;
                den2[r] = (h2)0.f;
            }
            const h2* kxP = (const h2*)(kx + dcol * 116);
            const h2* xP  = (const h2*)(xt + dcol * 56);
            for (int p = 0; p < NN / 2; ++p) {
                h2 Ek2 = kxP[2 * p];        // adjacent 8B-aligned -> ds_read_b64
                h2 ek2 = kxP[2 * p + 1];
                h2 x2  = xP[p];
#pragma unroll
                for (int r = 0; r < 4; ++r) {
                    h2 wv = __builtin_elementwise_max(rho2[r] * ek2, Ek2);
                    den2[r] = den2[r] + wv;
                    num2[r] = wv * x2 + num2[r];        // v_pk_fma_f16
                }
            }
#pragma unroll
            for (int r = 0; r < 4; ++r) {
                float nu = (float)num2[r].x + (float)num2[r].y;
                float de = (float)den2[r].x + (float)den2[r].y;
                att[r] = nu / de;
            }
        }
        __syncthreads();                 // kx fully read -> safe to alias xb
#pragma unroll
        for (int reg = 0; reg < 4; ++reg)
            xb[(i0 + reg) * 72 + dcol] = (unsigned short)f2bfbits(att[reg]);
        __syncthreads();

        // ---- phase 3: y = att @ Wl + bl on MFMA ----
        // (xb pad rows hold garbage att: affects only discarded C-rows >= 50)
        {
            const bf16x8 c0 = *(const bf16x8*)&xb[(tm * 16 + ln) * 72 + qd * 8];
            const bf16x8 c1 = *(const bf16x8*)&xb[(tm * 16 + ln) * 72 + 32 + qd * 8];
            const float bov = (L ? b2 : b1)[dcol];
            f32x4 y = {bov, bov, bov, bov};

            bf16x8 bf_;
            bf_ = *(const bf16x8*)&wot[dcol * 72 + qd * 8];
            y = __builtin_amdgcn_mfma_f32_16x16x32_bf16(c0, bf_, y, 0, 0, 0);
            bf_ = *(const bf16x8*)&wot[dcol * 72 + 32 + qd * 8];
            y = __builtin_amdgcn_mfma_f32_16x16x32_bf16(c1, bf_, y, 0, 0, 0);

            if (L == 0) {
                // att1 -> xa (bf16 rows; pad-row garbage contained) + xt (guarded)
#pragma unroll
                for (int reg = 0; reg < 4; ++reg) {
                    const int i = i0 + reg;
                    xa[i * 72 + dcol] = (unsigned short)f2bfbits(y[reg]);
                    if (i < NN) xt[dcol * 56 + i] = (_Float16)y[reg];
                }
                __syncthreads();
            } else {
                // stage fp32 y over dead kx-tail/xt, then coalesced store
#pragma unroll
                for (int reg = 0; reg < 4; ++reg) {
                    const int i = i0 + reg;
                    if (i < NN) yF[i * 64 + dcol] = y[reg];
                }
                __syncthreads();
                for (int idx = tid; idx < NN * ND; idx += 1024) {
                    const int i  = idx >> 6;
                    const int dd = idx & 63;
                    float e0   = embB[dd];
                    float ie   = embB[ND + idx];
                    float att1 = bfu(xa[i * 72 + dd]);
                    float o    = fmaf(e0, ie, yF[idx] + att1);
                    o = fmaxf(o, 0.01f * o);
                    out[(size_t)b * (NN * ND) + idx] = o;
                }
            }
        }
    }
}

extern "C" void kernel_launch(void* const* d_in, const int* in_sizes, int n_in,
                              void* d_out, int out_size, void* d_ws, size_t ws_size,
                              hipStream_t stream) {
    const float* emb = (const float*)d_in[0];
    const float* wa1 = (const float*)d_in[1];
    const float* ba1 = (const float*)d_in[2];
    const float* wa2 = (const float*)d_in[3];
    const float* ba2 = (const float*)d_in[4];
    const float* w1  = (const float*)d_in[5];
    const float* b1  = (const float*)d_in[6];
    const float* w2  = (const float*)d_in[7];
    const float* b2  = (const float*)d_in[8];
    float* out = (float*)d_out;

    att2_kernel<<<NB, 1024, 0, stream>>>(emb, wa1, ba1, wa2, ba2, w1, b1, w2, b2, out);
}